// Round 1
// baseline (1589.967 us; speedup 1.0000x reference)
//
#include <hip/hip_runtime.h>
#include <hip/hip_bf16.h>
#include <math.h>

// Problem dims (fixed)
#define TT   64
#define BBATCH 64
#define NTOK 64
#define DDIM 128
#define HIDN 256
#define BN   4096     // BBATCH*NTOK

typedef short bf16x8 __attribute__((ext_vector_type(8)));
typedef float f32x4  __attribute__((ext_vector_type(4)));

// ---------------------------------------------------------------------------
// G = C_low^T C_low : symmetric 64x64 Gram of the first 16 orthonormal DCT-II
// rows. lowpass_time(x) == G @ x along time (k=0 row makes the mean re-add
// exact in exact arithmetic; fp32 noise is the same class as matmul reorder).
// ---------------------------------------------------------------------------
__global__ void k_gram(float* __restrict__ G) {
  int s = blockIdx.x, t = threadIdx.x;
  double acc = 0.0;
  for (int k = 0; k < 16; ++k) {
    double ct, cs;
    if (k == 0) { ct = 0.125; cs = 0.125; }  // sqrt(1/64)
    else {
      const double f = 0.17677669529663687;  // sqrt(2/64)
      ct = cos(M_PI * (t + 0.5) * k / 64.0) * f;
      cs = cos(M_PI * (s + 0.5) * k / 64.0) * f;
    }
    acc += ct * cs;
  }
  G[s * 64 + t] = (float)acc;
}

// ---------------------------------------------------------------------------
// xlp[t,b,n,:] = sum_s G[t,s] * ( x[s,b,n,:] * (0.05*mx[n,b,s,:]+0.95*mx[n,b,s,:]) )
// One block per (b,n). m2 tile staged in LDS; G read via wave-uniform scalar
// loads (s is per-wave uniform); two s-halves reduced through LDS.
// ---------------------------------------------------------------------------
__global__ __launch_bounds__(256) void k_lowpass(
    const float* __restrict__ x, const float* __restrict__ mx,
    const float* __restrict__ G, float* __restrict__ xlp) {
  __shared__ float m2[64 * 132];  // [s][d], stride 132 (bank-safe, 16B aligned)
  const int bn = blockIdx.x;
  const int b = bn >> 6, n = bn & 63;
  const float* mxs = mx + (size_t)(n * 64 + b) * 8192;  // (n,b) slab, contiguous
#pragma unroll
  for (int i = 0; i < 8; ++i) {
    int idx4 = threadIdx.x + i * 256;          // 0..2047 float4s
    int s = idx4 >> 5, dq = (idx4 & 31) * 4;
    const float4 xv = *(const float4*)&x[(size_t)(s * 4096 + bn) * 128 + dq];
    const float4 mv = *(const float4*)&mxs[idx4 * 4];
    float4 r;
    {
#pragma clang fp contract(off)
      // replicate reference rounding: fl(fl(.05m)+fl(.95m)) then * x
      r.x = xv.x * (0.05f * mv.x + 0.95f * mv.x);
      r.y = xv.y * (0.05f * mv.y + 0.95f * mv.y);
      r.z = xv.z * (0.05f * mv.z + 0.95f * mv.z);
      r.w = xv.w * (0.05f * mv.w + 0.95f * mv.w);
    }
    *(float4*)&m2[s * 132 + dq] = r;
  }
  __syncthreads();
  const int d = threadIdx.x & 127, shh = threadIdx.x >> 7;  // s-half per wave-pair
  float acc[64];
#pragma unroll
  for (int t = 0; t < 64; ++t) acc[t] = 0.f;
  for (int si = 0; si < 32; ++si) {
    int s = shh * 32 + si;
    float mval = m2[s * 132 + d];
    const float* Gs = G + s * 64;  // wave-uniform -> s_load; G symmetric
#pragma unroll
    for (int t = 0; t < 64; ++t) acc[t] = fmaf(Gs[t], mval, acc[t]);
  }
  __syncthreads();
  float* part = m2;  // reuse LDS: [d][t] stride 66
  if (shh == 1) {
#pragma unroll
    for (int t = 0; t < 64; ++t) part[d * 66 + t] = acc[t];
  }
  __syncthreads();
  if (shh == 0) {
#pragma unroll
    for (int t = 0; t < 64; ++t) {
      float v = acc[t] + part[d * 66 + t];
      xlp[(size_t)(t * 4096 + bn) * 128 + d] = v;
    }
  }
}

// ---------------------------------------------------------------------------
// Fused GEMM + LIF (+ optional multiplicative gate) per (b,n):
//   pre[t][c] = sum_k A[(t,b,n)][k] * W[k][c0+c],  t=0..63, c=0..127
//   LIF scan over t per column; output either bf16 spike bits (0x3F80/0) or
//   gated fp32:  out = gate * (1 - spike)  (exact select since spike in {0,1}).
// A rows live at (t*4096+bn)*KDIM. Tiles: A[k][t] LDS stride 65 (conflict-free
// staged, 2-way-free read), B[k][c] stride 128. C reuses A/B LDS after barrier.
// ---------------------------------------------------------------------------
template <int KDIM, bool ABF16, bool GATE>
__global__ __launch_bounds__(256) void k_gemm_lif(
    const void* __restrict__ Ap, const float* __restrict__ W, const int NW,
    const float* __restrict__ gate, void* __restrict__ outp) {
  __shared__ float smem[64 * 65 + 64 * 128];  // 49408 B -> 3 blocks/CU
  float* Al = smem;
  float* Bl = smem + 64 * 65;
  const int bn = blockIdx.x;
  const int c0 = blockIdx.y * 128;
  const int mq = threadIdx.x & 15;   // t-quad: rows mq*4..mq*4+3
  const int ng = threadIdx.x >> 4;   // col-octet: cols ng*8..ng*8+7
  float acc[4][8];
#pragma unroll
  for (int i = 0; i < 4; ++i)
#pragma unroll
    for (int j = 0; j < 8; ++j) acc[i][j] = 0.f;

  for (int kc = 0; kc < KDIM; kc += 64) {
    {  // stage A chunk: lane = k (conflict-free LDS writes), 16 rows each
      const int k = threadIdx.x & 63, tq = threadIdx.x >> 6;
#pragma unroll
      for (int i = 0; i < 16; ++i) {
        int t = tq * 16 + i;
        size_t rowi = (size_t)(t * 4096 + bn) * KDIM + kc + k;
        float v;
        if (ABF16) {
          unsigned short bits = ((const unsigned short*)Ap)[rowi];
          v = __uint_as_float((unsigned)bits << 16);  // exact bf16->f32
        } else {
          v = ((const float*)Ap)[rowi];
        }
        Al[k * 65 + t] = v;
      }
    }
#pragma unroll
    for (int j = 0; j < 8; ++j) {  // stage B chunk (64x128 f32), float4 coalesced
      int idx = threadIdx.x + j * 256;
      int k = idx >> 5, cq = (idx & 31) * 4;
      *(float4*)&Bl[k * 128 + cq] = *(const float4*)&W[(size_t)(kc + k) * NW + c0 + cq];
    }
    __syncthreads();
#pragma unroll 4
    for (int k = 0; k < 64; ++k) {
      float av[4];
      av[0] = Al[k * 65 + mq * 4 + 0];
      av[1] = Al[k * 65 + mq * 4 + 1];
      av[2] = Al[k * 65 + mq * 4 + 2];
      av[3] = Al[k * 65 + mq * 4 + 3];
      float bv[8];
      *(float4*)&bv[0] = *(const float4*)&Bl[k * 128 + ng * 8];
      *(float4*)&bv[4] = *(const float4*)&Bl[k * 128 + ng * 8 + 4];
#pragma unroll
      for (int i = 0; i < 4; ++i)
#pragma unroll
        for (int j = 0; j < 8; ++j) acc[i][j] = fmaf(av[i], bv[j], acc[i][j]);
    }
    __syncthreads();
  }
  // scatter C tile to LDS [t][c] (stride 132), then LIF scan per column
  float* Cl = smem;
#pragma unroll
  for (int i = 0; i < 4; ++i) {
    *(float4*)&Cl[(mq * 4 + i) * 132 + ng * 8] =
        make_float4(acc[i][0], acc[i][1], acc[i][2], acc[i][3]);
    *(float4*)&Cl[(mq * 4 + i) * 132 + ng * 8 + 4] =
        make_float4(acc[i][4], acc[i][5], acc[i][6], acc[i][7]);
  }
  __syncthreads();
  if (threadIdx.x < 128) {
    const int c = threadIdx.x;
    float v = 0.f;
    for (int t = 0; t < 64; ++t) {
      float pre = Cl[t * 132 + c];
      {
#pragma clang fp contract(off)
        float dlt = (pre - v) * 0.5f;  // v + (c-v)/tau, tau=2 (exact /2)
        v = v + dlt;
      }
      bool s = (v >= 1.0f);
      size_t orow = (size_t)(t * 4096 + bn);
      if (GATE) {
        float g = gate[orow * 128 + c];
        ((float*)outp)[orow * 128 + c] = s ? 0.f : g;  // g*(1-s) exact
      } else {
        ((unsigned short*)outp)[orow * NW + c0 + c] =
            s ? (unsigned short)0x3F80 : (unsigned short)0;  // bf16 1.0 / 0.0
      }
      v = s ? 0.f : v;  // hard reset
    }
  }
}

// ---------------------------------------------------------------------------
// Spiking 2-head attention per (t,b):  S = q k^T * 0.125 ; O = S v. No softmax.
// Exact in bf16 MFMA: spikes in {0,1}; S integer<=64 (bf16-exact after *1/8);
// O = multiples of 1/8 <= 512 (fp32-exact). Wave w owns n-rows [w*16,w*16+16).
// ---------------------------------------------------------------------------
__global__ __launch_bounds__(256) void k_attn(
    const unsigned short* __restrict__ q, const unsigned short* __restrict__ kk,
    const unsigned short* __restrict__ vv, float* __restrict__ o) {
  __shared__ unsigned short ql[64 * 136];  // [n][d] bf16 bits
  __shared__ unsigned short kl[64 * 136];
  __shared__ unsigned short vt[128 * 72];  // [d][m] (v transposed)
  __shared__ unsigned short sl[64 * 72];   // S' [n][m] per head (reused)
  const size_t base = (size_t)blockIdx.x * 8192;
#pragma unroll
  for (int i = 0; i < 4; ++i) {
    int idx8 = threadIdx.x + i * 256;     // 1024 x 8-elem chunks
    int n = idx8 >> 4, d8 = (idx8 & 15) * 8;
    uint4 pq = *(const uint4*)&q[base + n * 128 + d8];
    uint4 pk = *(const uint4*)&kk[base + n * 128 + d8];
    *(uint4*)&ql[n * 136 + d8] = pq;
    *(uint4*)&kl[n * 136 + d8] = pk;
    uint4 pv = *(const uint4*)&vv[base + n * 128 + d8];
    unsigned short e[8] = {
        (unsigned short)(pv.x & 0xFFFF), (unsigned short)(pv.x >> 16),
        (unsigned short)(pv.y & 0xFFFF), (unsigned short)(pv.y >> 16),
        (unsigned short)(pv.z & 0xFFFF), (unsigned short)(pv.z >> 16),
        (unsigned short)(pv.w & 0xFFFF), (unsigned short)(pv.w >> 16)};
#pragma unroll
    for (int j = 0; j < 8; ++j) vt[(d8 + j) * 72 + n] = e[j];
  }
  __syncthreads();
  const int lane = threadIdx.x & 63;
  const int w = threadIdx.x >> 6;          // wave id = n-tile (ti)
  const int l15 = lane & 15, l4 = lane >> 4;
  for (int h = 0; h < 2; ++h) {
    // phase 1: S tiles (ti=w, tj=0..3), K = dh = 64 (2 MFMA k-steps)
    bf16x8 af0 = *(const bf16x8*)&ql[(w * 16 + l15) * 136 + h * 64 + l4 * 8];
    bf16x8 af1 = *(const bf16x8*)&ql[(w * 16 + l15) * 136 + h * 64 + 32 + l4 * 8];
#pragma unroll
    for (int tj = 0; tj < 4; ++tj) {
      f32x4 c = {0.f, 0.f, 0.f, 0.f};
      bf16x8 b0 = *(const bf16x8*)&kl[(tj * 16 + l15) * 136 + h * 64 + l4 * 8];
      c = __builtin_amdgcn_mfma_f32_16x16x32_bf16(af0, b0, c, 0, 0, 0);
      bf16x8 b1 = *(const bf16x8*)&kl[(tj * 16 + l15) * 136 + h * 64 + 32 + l4 * 8];
      c = __builtin_amdgcn_mfma_f32_16x16x32_bf16(af1, b1, c, 0, 0, 0);
#pragma unroll
      for (int r = 0; r < 4; ++r) {
        float sp = c[r] * 0.125f;  // exact; low 16 mantissa bits are zero
        sl[(w * 16 + l4 * 4 + r) * 72 + tj * 16 + l15] =
            (unsigned short)(__float_as_uint(sp) >> 16);
      }
    }
    __syncthreads();
    // phase 2: O tiles (ti=w, tj over dh), K = m = 64
    bf16x8 a20 = *(const bf16x8*)&sl[(w * 16 + l15) * 72 + l4 * 8];
    bf16x8 a21 = *(const bf16x8*)&sl[(w * 16 + l15) * 72 + 32 + l4 * 8];
#pragma unroll
    for (int tj = 0; tj < 4; ++tj) {
      f32x4 c = {0.f, 0.f, 0.f, 0.f};
      bf16x8 b0 = *(const bf16x8*)&vt[(h * 64 + tj * 16 + l15) * 72 + l4 * 8];
      c = __builtin_amdgcn_mfma_f32_16x16x32_bf16(a20, b0, c, 0, 0, 0);
      bf16x8 b1 = *(const bf16x8*)&vt[(h * 64 + tj * 16 + l15) * 72 + 32 + l4 * 8];
      c = __builtin_amdgcn_mfma_f32_16x16x32_bf16(a21, b1, c, 0, 0, 0);
#pragma unroll
      for (int r = 0; r < 4; ++r)
        o[base + (size_t)(w * 16 + l4 * 4 + r) * 128 + h * 64 + tj * 16 + l15] = c[r];
    }
    __syncthreads();  // sl reused by next head
  }
}

// ---------------------------------------------------------------------------
extern "C" void kernel_launch(void* const* d_in, const int* in_sizes, int n_in,
                              void* d_out, int out_size, void* d_ws, size_t ws_size,
                              hipStream_t stream) {
  const float* x  = (const float*)d_in[0];
  const float* mx = (const float*)d_in[1];
  const float* Wq = (const float*)d_in[2];
  const float* Wk = (const float*)d_in[3];
  const float* Wv = (const float*)d_in[4];
  const float* Wo = (const float*)d_in[5];
  const float* W1 = (const float*)d_in[6];
  const float* W2 = (const float*)d_in[7];
  float* out = (float*)d_out;

  // workspace layout (~470 MB):
  char* w = (char*)d_ws;
  float* G   = (float*)w;                                   // 16 KB (pad 64K)
  float* xlp = (float*)(w + 65536);                         // 134 MB, later o
  float* x2  = (float*)(w + 65536 + 134217728ull);          // 134 MB
  unsigned short* sq = (unsigned short*)(w + 65536 + 268435456ull);  // 67 MB
  unsigned short* sk = sq + 33554432ull;                    // 67 MB
  unsigned short* sv = sk + 33554432ull;                    // 67 MB
  unsigned short* sh = sq;  // mlp hidden spikes overlay sq+sk (134 MB)

  k_gram<<<64, 64, 0, stream>>>(G);
  k_lowpass<<<4096, 256, 0, stream>>>(x, mx, G, xlp);
  // q from x; k,v from lowpassed memory stream
  k_gemm_lif<128, false, false><<<dim3(4096, 1), 256, 0, stream>>>(x,   Wq, 128, nullptr, sq);
  k_gemm_lif<128, false, false><<<dim3(4096, 1), 256, 0, stream>>>(xlp, Wk, 128, nullptr, sk);
  k_gemm_lif<128, false, false><<<dim3(4096, 1), 256, 0, stream>>>(xlp, Wv, 128, nullptr, sv);
  k_attn<<<4096, 256, 0, stream>>>(sq, sk, sv, xlp);  // o overwrites xlp
  // attn_spk = lif(o @ Wo); x2 = x * (1 - attn_spk)
  k_gemm_lif<128, false, true ><<<dim3(4096, 1), 256, 0, stream>>>(xlp, Wo, 128, x, x2);
  // mlp: h = lif(x2 @ W1) (HID=256 -> grid.y=2); out = x2 * (1 - lif(h @ W2))
  k_gemm_lif<128, false, false><<<dim3(4096, 2), 256, 0, stream>>>(x2, W1, 256, nullptr, sh);
  k_gemm_lif<256, true,  true ><<<dim3(4096, 1), 256, 0, stream>>>(sh, W2, 128, x2, out);
}